// Round 8
// baseline (181.778 us; speedup 1.0000x reference)
//
#include <hip/hip_runtime.h>

#define N_NODES 50000
#define BATCH   4
#define N_EDGES 500000
#define H_SIZE  64

#define NSEG   (BATCH * N_NODES)            // 200,000 segments (b, src)
#define NEDGE  (BATCH * N_EDGES)            // 2,000,000 edges

#define SPB    128                          // segments per bucket (seg>>7)
#define CB     ((NSEG + SPB - 1) / SPB)     // 1563 buckets
#define CAP    2048                         // per-bucket LDS edge cap (mean 1280, +21 sigma)
#define CHUNK  4096                         // edges per bin block (= 8/thread exactly)
#define NCHUNK ((NEDGE + CHUNK - 1) / CHUNK) // 489 (<512, fits one scan row)
#define AUXW   (CB + 1)                     // aux row: starts + sentinel
#define BINS   2048                         // padded bin count (>= CB+1)
#define PAIRN  ((long long)NCHUNK * CHUNK)  // allocated pair entries

// ---------- Phase 1: per-chunk bucket binning ----------
// pair.x = (sl<<18) | gdst  where sl = seg&127, gdst = b*N_NODES+dst (<2^18)
// Edge regs compile-time indexed (no scratch); shfl-based scans (2 barriers).
__global__ __launch_bounds__(512) void bin_kernel(
    const float* __restrict__ ew, ushort* __restrict__ aux,
    int2* __restrict__ pair)
{
    __shared__ int2 st[CHUNK];     // 32 KB sorted staging
    __shared__ int cnt[BINS];      // 8 KB
    __shared__ int scn[BINS];      // 8 KB (starts -> placement cursors)
    __shared__ int wsum[8];
    const int c = blockIdx.x;
    const int tid = threadIdx.x;
    const int lane = tid & 63, wv = tid >> 6;
    const int e0 = c * CHUNK;
    const int n = min(CHUNK, NEDGE - e0);

    for (int i = tid; i < BINS; i += 512) cnt[i] = 0;
    __syncthreads();

    // exactly 8 edges per thread, compile-time indexed (no scratch)
    int2 ev[8];
    int  ecb[8];
    #pragma unroll
    for (int k = 0; k < 8; ++k) {
        int i = tid + 512 * k;
        if (i < n) {
            int e = e0 + i;
            long long eb = (long long)e * 3;
            int b = e / N_EDGES;
            int src = (int)ew[eb];
            int dst = (int)ew[eb + 1];
            float w = ew[eb + 2];
            src = min(max(src, 0), N_NODES - 1);
            dst = min(max(dst, 0), N_NODES - 1);
            int seg = b * N_NODES + src;
            int cb = seg >> 7, sl = seg & (SPB - 1);
            int2 v; v.x = (sl << 18) | (b * N_NODES + dst); v.y = __float_as_int(w);
            ev[k] = v; ecb[k] = cb;
            atomicAdd(&cnt[cb], 1);
        } else {
            ecb[k] = -1;
        }
    }
    __syncthreads();

    // exclusive scan of 2048 bins: 4 bins/thread + shfl wave scan
    int c0 = cnt[4 * tid], c1 = cnt[4 * tid + 1];
    int c2 = cnt[4 * tid + 2], c3 = cnt[4 * tid + 3];
    int s0 = c0, s01 = c0 + c1, s012 = s01 + c2, tot = s012 + c3;
    int iv = tot;
    #pragma unroll
    for (int off = 1; off < 64; off <<= 1) {
        int t = __shfl_up(iv, off, 64);
        if (lane >= off) iv += t;
    }
    if (lane == 63) wsum[wv] = iv;
    __syncthreads();
    int wbase = 0;
    #pragma unroll
    for (int k = 0; k < 8; ++k) wbase += (k < wv) ? wsum[k] : 0;
    int base = wbase + iv - tot;          // exclusive prefix of this thread's 4 bins
    scn[4 * tid]     = base;
    scn[4 * tid + 1] = base + s0;
    scn[4 * tid + 2] = base + s01;
    scn[4 * tid + 3] = base + s012;
    __syncthreads();

    // write chunk-local bucket starts (before cursors get consumed)
    for (int i = tid; i < AUXW; i += 512)
        aux[(long long)c * AUXW + i] = (ushort)scn[i];
    __syncthreads();

    // place edges into sorted LDS staging (compile-time k)
    #pragma unroll
    for (int k = 0; k < 8; ++k) {
        if (ecb[k] >= 0) {
            int pos = atomicAdd(&scn[ecb[k]], 1);
            st[min(pos, CHUNK - 1)] = ev[k];
        }
    }
    __syncthreads();

    // coalesced writeout (2 edges = int4 per op)
    for (int i = 2 * tid; i + 1 < n; i += 1024)
        *(int4*)(pair + (long long)e0 + i) = *(const int4*)(st + i);
    if (tid == 0 && (n & 1)) pair[(long long)e0 + n - 1] = st[n - 1];
}

// XCD-affinity bijective block->bucket map (proven in R7: FETCH 125->76 MB).
__device__ __forceinline__ int swz_cb(int bid)
{
    const int q = CB >> 3, r = CB & 7;     // 195, 3
    int xcd = bid & 7, idx = bid >> 3;
    return (xcd < r) ? (xcd * (q + 1) + idx)
                     : (r * (q + 1) + (xcd - r) * q + idx);
}

// ---------- Phase 2: fused counting-sort (LDS) + register gather ----------
// fp32 H direct (no bf16 mirror). Inner loop: 8 edges/round, 4 H-loads in
// flight per lane (2x MLP vs R7). Index select dropped: sps padded by 8
// initialized entries; w-select zeroes out-of-range contributions; gdst
// clamp keeps every H address in-bounds (garbage-safe).
__global__ __launch_bounds__(512) void sortgather_f32(
    const float* __restrict__ H, const ushort* __restrict__ aux,
    const int2* __restrict__ pair, float* __restrict__ out)
{
    __shared__ int2 spu[CAP];          // 16 KB unsorted staging
    __shared__ int2 sps[CAP + 8];      // 16 KB + pad sorted
    __shared__ int rb[512];            // inclusive run-length scan
    __shared__ int roff[512];          // run start offset within chunk
    __shared__ int cnt[SPB];
    __shared__ int scn[SPB];
    __shared__ int lcur[SPB];
    __shared__ int wsum[8];
    const int cb = swz_cb(blockIdx.x);
    const int tid = threadIdx.x;
    const int lane = tid & 63, wv = tid >> 6;

    // run descriptor for chunk tid
    int off0 = 0, len = 0;
    if (tid < NCHUNK) {
        int a0 = (int)aux[(long long)tid * AUXW + cb];
        int a1 = (int)aux[(long long)tid * AUXW + cb + 1];
        a0 = min(a0, CHUNK); a1 = min(a1, CHUNK);
        off0 = a0; len = max(a1 - a0, 0);
    }
    roff[tid] = off0;
    for (int i = tid; i < SPB; i += 512) { cnt[i] = 0; lcur[i] = 0; }

    // shfl-based inclusive scan of run lengths -> rb[]
    int iv = len;
    #pragma unroll
    for (int off = 1; off < 64; off <<= 1) {
        int t = __shfl_up(iv, off, 64);
        if (lane >= off) iv += t;
    }
    if (lane == 63) wsum[wv] = iv;
    __syncthreads();
    int wbase = 0;
    #pragma unroll
    for (int k = 0; k < 8; ++k) wbase += (k < wv) ? wsum[k] : 0;
    rb[tid] = wbase + iv;
    __syncthreads();
    const int nb = min(rb[511], CAP);

    // cooperative copy: edge i -> (chunk j, local) via binary search over rb
    for (int i = tid; i < nb; i += 512) {
        int j = 0;
        #pragma unroll
        for (int s = 256; s > 0; s >>= 1) {
            int k = j + s;
            if (k <= 512 && rb[k - 1] <= i) j = k;
        }
        j = min(j, 511);
        int prev = (j > 0) ? rb[j - 1] : 0;
        int local = i - prev;
        long long pidx = (long long)j * CHUNK + roff[j] + local;
        pidx = min(max(pidx, 0LL), PAIRN - 1);
        int2 v = pair[pidx];
        spu[i] = v;
        atomicAdd(&cnt[(v.x >> 18) & (SPB - 1)], 1);
    }
    __syncthreads();

    // exclusive scan of SPB bins (shfl scan + cross-wave base)
    int cv = (tid < SPB) ? cnt[tid] : 0;
    int iv2 = cv;
    #pragma unroll
    for (int off = 1; off < 64; off <<= 1) {
        int t = __shfl_up(iv2, off, 64);
        if (lane >= off) iv2 += t;
    }
    if (tid == 63) wsum[0] = iv2;
    __syncthreads();
    if (tid < SPB) scn[tid] = iv2 - cv + ((tid >= 64) ? wsum[0] : 0);
    __syncthreads();

    // LDS -> LDS counting sort
    for (int i = tid; i < nb; i += 512) {
        int2 v = spu[i];
        int sl = (v.x >> 18) & (SPB - 1);
        int pos = scn[sl] + atomicAdd(&lcur[sl], 1);
        pos = min(max(pos, 0), CAP - 1);
        sps[pos] = v;
    }
    // init 8-entry pad past nb (read by the unguarded loads; w=0 kills them)
    if (tid < 8) { int2 z; z.x = 0; z.y = 0; sps[min(nb + tid, CAP + 7)] = z; }
    __syncthreads();

    // gather: wave w owns segments w*16 .. w*16+15; 8 edges/round
    const int wid  = tid >> 6;
    const int half = lane >> 5;
    const int sub  = lane & 31;
    const float2* H2 = (const float2*)H;

    for (int s = 0; s < 16; ++s) {
        int sl = wid * 16 + s;
        int st = scn[sl];
        int en = st + cnt[sl];
        float ax = 0.f, ay = 0.f;
        for (int i = st; i < en; i += 8) {
            int2 p0 = sps[i + half];
            int2 p1 = sps[i + 2 + half];
            int2 p2 = sps[i + 4 + half];
            int2 p3 = sps[i + 6 + half];
            float2 h0 = H2[((uint)min(p0.x & 0x3FFFF, NSEG - 1) << 5) + sub];
            float2 h1 = H2[((uint)min(p1.x & 0x3FFFF, NSEG - 1) << 5) + sub];
            float2 h2 = H2[((uint)min(p2.x & 0x3FFFF, NSEG - 1) << 5) + sub];
            float2 h3 = H2[((uint)min(p3.x & 0x3FFFF, NSEG - 1) << 5) + sub];
            float w0 = (i + half     < en) ? __int_as_float(p0.y) : 0.0f;
            float w1 = (i + 2 + half < en) ? __int_as_float(p1.y) : 0.0f;
            float w2 = (i + 4 + half < en) ? __int_as_float(p2.y) : 0.0f;
            float w3 = (i + 6 + half < en) ? __int_as_float(p3.y) : 0.0f;
            ax = fmaf(w0, h0.x, ax);
            ay = fmaf(w0, h0.y, ay);
            ax = fmaf(w1, h1.x, ax);
            ay = fmaf(w1, h1.y, ay);
            ax = fmaf(w2, h2.x, ax);
            ay = fmaf(w2, h2.y, ay);
            ax = fmaf(w3, h3.x, ax);
            ay = fmaf(w3, h3.y, ay);
        }
        ax += __shfl_xor(ax, 32, 64);
        ay += __shfl_xor(ay, 32, 64);
        int seg = (cb << 7) + sl;
        if (half == 0 && seg < NSEG) {
            float2 v2; v2.x = ax; v2.y = ay;
            ((float2*)out)[((long long)seg << 5) + sub] = v2;
        }
    }
}

// ---------- Fallback path (ws too small): zero + atomic scatter ----------
__global__ __launch_bounds__(256) void zero_kernel(int* __restrict__ p, long long n)
{
    long long i = (long long)blockIdx.x * blockDim.x + threadIdx.x;
    if (i < n) p[i] = 0;
}

__global__ __launch_bounds__(256) void atomic_kernel(
    const float* __restrict__ H, const float* __restrict__ ew,
    float* __restrict__ out)
{
    const long long gid = (long long)blockIdx.x * blockDim.x + threadIdx.x;
    const long long wave = gid >> 6;
    const int lane = threadIdx.x & 63;
    if (wave >= (long long)NEDGE) return;
    const int b = (int)(wave / N_EDGES);
    const long long ebase = wave * 3;
    const int src = (int)ew[ebase + 0];
    const int dst = (int)ew[ebase + 1];
    const float w = ew[ebase + 2];
    atomicAdd(&out[((long long)b * N_NODES + src) * H_SIZE + lane],
              w * H[((long long)b * N_NODES + dst) * H_SIZE + lane]);
}

extern "C" void kernel_launch(void* const* d_in, const int* in_sizes, int n_in,
                              void* d_out, int out_size, void* d_ws, size_t ws_size,
                              hipStream_t stream) {
    const float* H  = (const float*)d_in[0];   // (B, N, 64) fp32
    const float* ew = (const float*)d_in[1];   // (B, E, 3) fp32
    float* out = (float*)d_out;                // (B, N, 64) fp32

    // ws layout: aux[NCHUNK*AUXW]ushort | (16B) pair[NCHUNK*CHUNK]int2
    const size_t aux_bytes = (size_t)NCHUNK * AUXW * 2;
    const size_t p_off = (aux_bytes + 15) & ~(size_t)15;
    const size_t need = p_off + (size_t)PAIRN * 8;      // ~17.6 MB

    if (ws_size < need) {
        long long n = out_size;
        zero_kernel<<<(unsigned)((n + 255) / 256), 256, 0, stream>>>((int*)out, n);
        const long long total = (long long)NEDGE * 64;
        atomic_kernel<<<(unsigned)((total + 255) / 256), 256, 0, stream>>>(H, ew, out);
        return;
    }

    ushort* aux = (ushort*)d_ws;
    int2* pair  = (int2*)((char*)d_ws + p_off);

    bin_kernel<<<NCHUNK, 512, 0, stream>>>(ew, aux, pair);
    sortgather_f32<<<CB, 512, 0, stream>>>(H, aux, pair, out);
}

// Round 9
// 164.535 us; speedup vs baseline: 1.1048x; 1.1048x over previous
//
#include <hip/hip_runtime.h>

#define N_NODES 50000
#define BATCH   4
#define N_EDGES 500000
#define H_SIZE  64

#define NSEG   (BATCH * N_NODES)            // 200,000 segments (b, src)
#define NEDGE  (BATCH * N_EDGES)            // 2,000,000 edges
#define NHEL   ((long long)BATCH * N_NODES * H_SIZE)   // 12.8M H elems

#define SPB    128                          // segments per bucket (seg>>7)
#define CB     ((NSEG + SPB - 1) / SPB)     // 1563 buckets
#define CAP    2048                         // per-bucket LDS edge cap (mean 1280, +21 sigma)
#define CHUNK  4096                         // edges per bin block (= 8/thread exactly)
#define NCHUNK ((NEDGE + CHUNK - 1) / CHUNK) // 489 (<512, fits one scan row)
#define AUXW   (CB + 1)                     // aux row: starts + sentinel
#define BINS   2048                         // padded bin count (>= CB+1)
#define PAIRN  ((long long)NCHUNK * CHUNK)  // allocated pair entries

// ---------- Phase 1: per-chunk bucket binning + fused H->bf16 cvt ----------
// (R7 structure: compile-time-indexed edge regs, shfl scans, coalesced out.)
// pair.x = (sl<<18) | gdst  where sl = seg&127, gdst = b*N_NODES+dst (<2^18)
__global__ __launch_bounds__(512) void bin_kernel(
    const float* __restrict__ ew, ushort* __restrict__ aux,
    int2* __restrict__ pair,
    const float* __restrict__ H, ushort* __restrict__ Hb16, int do_cvt)
{
    __shared__ int2 st[CHUNK];     // 32 KB sorted staging
    __shared__ int cnt[BINS];      // 8 KB
    __shared__ int scn[BINS];      // 8 KB (starts -> placement cursors)
    __shared__ int wsum[8];
    const int c = blockIdx.x;
    const int tid = threadIdx.x;
    const int lane = tid & 63, wv = tid >> 6;
    const int e0 = c * CHUNK;
    const int n = min(CHUNK, NEDGE - e0);

    for (int i = tid; i < BINS; i += 512) cnt[i] = 0;
    __syncthreads();

    // exactly 8 edges per thread, compile-time indexed (no scratch)
    int2 ev[8];
    int  ecb[8];
    #pragma unroll
    for (int k = 0; k < 8; ++k) {
        int i = tid + 512 * k;
        if (i < n) {
            int e = e0 + i;
            long long eb = (long long)e * 3;
            int b = e / N_EDGES;
            int src = (int)ew[eb];
            int dst = (int)ew[eb + 1];
            float w = ew[eb + 2];
            src = min(max(src, 0), N_NODES - 1);
            dst = min(max(dst, 0), N_NODES - 1);
            int seg = b * N_NODES + src;
            int cb = seg >> 7, sl = seg & (SPB - 1);
            int2 v; v.x = (sl << 18) | (b * N_NODES + dst); v.y = __float_as_int(w);
            ev[k] = v; ecb[k] = cb;
            atomicAdd(&cnt[cb], 1);
        } else {
            ecb[k] = -1;
        }
    }
    __syncthreads();

    // exclusive scan of 2048 bins: 4 bins/thread + shfl wave scan
    int c0 = cnt[4 * tid], c1 = cnt[4 * tid + 1];
    int c2 = cnt[4 * tid + 2], c3 = cnt[4 * tid + 3];
    int s0 = c0, s01 = c0 + c1, s012 = s01 + c2, tot = s012 + c3;
    int iv = tot;
    #pragma unroll
    for (int off = 1; off < 64; off <<= 1) {
        int t = __shfl_up(iv, off, 64);
        if (lane >= off) iv += t;
    }
    if (lane == 63) wsum[wv] = iv;
    __syncthreads();
    int wbase = 0;
    #pragma unroll
    for (int k = 0; k < 8; ++k) wbase += (k < wv) ? wsum[k] : 0;
    int base = wbase + iv - tot;          // exclusive prefix of this thread's 4 bins
    scn[4 * tid]     = base;
    scn[4 * tid + 1] = base + s0;
    scn[4 * tid + 2] = base + s01;
    scn[4 * tid + 3] = base + s012;
    __syncthreads();

    // write chunk-local bucket starts (before cursors get consumed)
    for (int i = tid; i < AUXW; i += 512)
        aux[(long long)c * AUXW + i] = (ushort)scn[i];
    __syncthreads();

    // place edges into sorted LDS staging (compile-time k)
    #pragma unroll
    for (int k = 0; k < 8; ++k) {
        if (ecb[k] >= 0) {
            int pos = atomicAdd(&scn[ecb[k]], 1);
            st[min(pos, CHUNK - 1)] = ev[k];
        }
    }
    __syncthreads();

    // coalesced writeout (2 edges = int4 per op)
    for (int i = 2 * tid; i + 1 < n; i += 1024)
        *(int4*)(pair + (long long)e0 + i) = *(const int4*)(st + i);
    if (tid == 0 && (n & 1)) pair[(long long)e0 + n - 1] = st[n - 1];

    // fused cvt: H fp32 -> bf16 (RNE), grid-stride
    if (do_cvt) {
        const long long stride = (long long)NCHUNK * 512 * 4;
        for (long long i = ((long long)c * 512 + tid) * 4; i < NHEL; i += stride) {
            float4 f = *(const float4*)(H + i);
            ushort4 u;
            uint v;
            v = __float_as_uint(f.x); u.x = (ushort)((v + 0x7FFF + ((v >> 16) & 1)) >> 16);
            v = __float_as_uint(f.y); u.y = (ushort)((v + 0x7FFF + ((v >> 16) & 1)) >> 16);
            v = __float_as_uint(f.z); u.z = (ushort)((v + 0x7FFF + ((v >> 16) & 1)) >> 16);
            v = __float_as_uint(f.w); u.w = (ushort)((v + 0x7FFF + ((v >> 16) & 1)) >> 16);
            *(ushort4*)(Hb16 + i) = u;
        }
    }
}

// XCD-affinity bijective block->bucket map (proven R7: FETCH 125->76 MB;
// bf16 per-XCD slice ~3.2 MB fits the 4 MB L2 -- key to why bf16 > fp32).
__device__ __forceinline__ int swz_cb(int bid)
{
    const int q = CB >> 3, r = CB & 7;     // 195, 3
    int xcd = bid & 7, idx = bid >> 3;
    return (xcd < r) ? (xcd * (q + 1) + idx)
                     : (r * (q + 1) + (xcd - r) * q + idx);
}

// ---------- Phase 2: fused counting-sort (LDS) + register gather ----------
// Paired-segment gather: segments s, s+1 processed concurrently -> 4
// independent H-loads in flight per lane (2x MLP vs R7) at ~20% slot waste.
// sps has a 16-entry zero pad so the index select is gone; w-select zeroes
// out-of-range contributions; every index clamped (R5 lesson).
__global__ __launch_bounds__(512) void sortgather_bf16(
    const ushort* __restrict__ Hb16, const ushort* __restrict__ aux,
    const int2* __restrict__ pair, float* __restrict__ out)
{
    __shared__ int2 spu[CAP];          // 16 KB unsorted staging
    __shared__ int2 sps[CAP + 16];     // 16 KB + pad sorted
    __shared__ int rb[512];            // inclusive run-length scan
    __shared__ int roff[512];          // run start offset within chunk
    __shared__ int cnt[SPB];
    __shared__ int scn[SPB];
    __shared__ int lcur[SPB];
    __shared__ int wsum[8];
    const int cb = swz_cb(blockIdx.x);
    const int tid = threadIdx.x;
    const int lane = tid & 63, wv = tid >> 6;

    // run descriptor for chunk tid
    int off0 = 0, len = 0;
    if (tid < NCHUNK) {
        int a0 = (int)aux[(long long)tid * AUXW + cb];
        int a1 = (int)aux[(long long)tid * AUXW + cb + 1];
        a0 = min(a0, CHUNK); a1 = min(a1, CHUNK);
        off0 = a0; len = max(a1 - a0, 0);
    }
    roff[tid] = off0;
    for (int i = tid; i < SPB; i += 512) { cnt[i] = 0; lcur[i] = 0; }

    // shfl-based inclusive scan of run lengths -> rb[]
    int iv = len;
    #pragma unroll
    for (int off = 1; off < 64; off <<= 1) {
        int t = __shfl_up(iv, off, 64);
        if (lane >= off) iv += t;
    }
    if (lane == 63) wsum[wv] = iv;
    __syncthreads();
    int wbase = 0;
    #pragma unroll
    for (int k = 0; k < 8; ++k) wbase += (k < wv) ? wsum[k] : 0;
    rb[tid] = wbase + iv;
    __syncthreads();
    const int nb = min(rb[511], CAP);

    // cooperative copy: edge i -> (chunk j, local) via binary search over rb
    for (int i = tid; i < nb; i += 512) {
        int j = 0;
        #pragma unroll
        for (int s = 256; s > 0; s >>= 1) {
            int k = j + s;
            if (k <= 512 && rb[k - 1] <= i) j = k;
        }
        j = min(j, 511);
        int prev = (j > 0) ? rb[j - 1] : 0;
        int local = i - prev;
        long long pidx = (long long)j * CHUNK + roff[j] + local;
        pidx = min(max(pidx, 0LL), PAIRN - 1);
        int2 v = pair[pidx];
        spu[i] = v;
        atomicAdd(&cnt[(v.x >> 18) & (SPB - 1)], 1);
    }
    __syncthreads();

    // exclusive scan of SPB bins (shfl scan + cross-wave base)
    int cv = (tid < SPB) ? cnt[tid] : 0;
    int iv2 = cv;
    #pragma unroll
    for (int off = 1; off < 64; off <<= 1) {
        int t = __shfl_up(iv2, off, 64);
        if (lane >= off) iv2 += t;
    }
    if (tid == 63) wsum[0] = iv2;
    __syncthreads();
    if (tid < SPB) scn[tid] = iv2 - cv + ((tid >= 64) ? wsum[0] : 0);
    __syncthreads();

    // LDS -> LDS counting sort
    for (int i = tid; i < nb; i += 512) {
        int2 v = spu[i];
        int sl = (v.x >> 18) & (SPB - 1);
        int pos = scn[sl] + atomicAdd(&lcur[sl], 1);
        pos = min(max(pos, 0), CAP - 1);
        sps[pos] = v;
    }
    // zero 16-entry pad past nb (read by unguarded loads; w=0 kills them)
    if (tid < 16) { int2 z; z.x = 0; z.y = 0; sps[min(nb + tid, CAP + 15)] = z; }
    __syncthreads();

    // gather: wave w owns segments w*16 .. w*16+15, processed in pairs
    const int wid  = tid >> 6;
    const int half = lane >> 5;
    const int sub  = lane & 31;
    const uint* H32 = (const uint*)Hb16;

    for (int s = 0; s < 16; s += 2) {
        int slA = wid * 16 + s, slB = slA + 1;
        int stA = scn[slA], enA = stA + cnt[slA];
        int stB = scn[slB], enB = stB + cnt[slB];
        int rounds = (max(enA - stA, enB - stB) + 3) >> 2;
        float axA = 0.f, ayA = 0.f, axB = 0.f, ayB = 0.f;
        int iA = stA, iB = stB;
        for (int r = 0; r < rounds; ++r, iA += 4, iB += 4) {
            int eA0 = iA + half, eA1 = iA + 2 + half;
            int eB0 = iB + half, eB1 = iB + 2 + half;
            int2 pA0 = sps[min(eA0, CAP + 15)];
            int2 pA1 = sps[min(eA1, CAP + 15)];
            int2 pB0 = sps[min(eB0, CAP + 15)];
            int2 pB1 = sps[min(eB1, CAP + 15)];
            uint hA0 = H32[((uint)min(pA0.x & 0x3FFFF, NSEG - 1) << 5) + sub];
            uint hA1 = H32[((uint)min(pA1.x & 0x3FFFF, NSEG - 1) << 5) + sub];
            uint hB0 = H32[((uint)min(pB0.x & 0x3FFFF, NSEG - 1) << 5) + sub];
            uint hB1 = H32[((uint)min(pB1.x & 0x3FFFF, NSEG - 1) << 5) + sub];
            float wA0 = (eA0 < enA) ? __int_as_float(pA0.y) : 0.0f;
            float wA1 = (eA1 < enA) ? __int_as_float(pA1.y) : 0.0f;
            float wB0 = (eB0 < enB) ? __int_as_float(pB0.y) : 0.0f;
            float wB1 = (eB1 < enB) ? __int_as_float(pB1.y) : 0.0f;
            axA = fmaf(wA0, __uint_as_float(hA0 << 16), axA);
            ayA = fmaf(wA0, __uint_as_float(hA0 & 0xFFFF0000u), ayA);
            axA = fmaf(wA1, __uint_as_float(hA1 << 16), axA);
            ayA = fmaf(wA1, __uint_as_float(hA1 & 0xFFFF0000u), ayA);
            axB = fmaf(wB0, __uint_as_float(hB0 << 16), axB);
            ayB = fmaf(wB0, __uint_as_float(hB0 & 0xFFFF0000u), ayB);
            axB = fmaf(wB1, __uint_as_float(hB1 << 16), axB);
            ayB = fmaf(wB1, __uint_as_float(hB1 & 0xFFFF0000u), ayB);
        }
        axA += __shfl_xor(axA, 32, 64);
        ayA += __shfl_xor(ayA, 32, 64);
        axB += __shfl_xor(axB, 32, 64);
        ayB += __shfl_xor(ayB, 32, 64);
        if (half == 0) {
            int segA = (cb << 7) + slA;
            int segB = segA + 1;
            if (segA < NSEG) {
                float2 v2; v2.x = axA; v2.y = ayA;
                ((float2*)out)[((long long)segA << 5) + sub] = v2;
            }
            if (segB < NSEG) {
                float2 v2; v2.x = axB; v2.y = ayB;
                ((float2*)out)[((long long)segB << 5) + sub] = v2;
            }
        }
    }
}

// fp32 fallback gather (workspace too small for the bf16 mirror) — R8's
// proven ILP-8 variant.
__global__ __launch_bounds__(512) void sortgather_f32(
    const float* __restrict__ H, const ushort* __restrict__ aux,
    const int2* __restrict__ pair, float* __restrict__ out)
{
    __shared__ int2 spu[CAP];
    __shared__ int2 sps[CAP + 8];
    __shared__ int rb[512];
    __shared__ int roff[512];
    __shared__ int cnt[SPB];
    __shared__ int scn[SPB];
    __shared__ int lcur[SPB];
    __shared__ int wsum[8];
    const int cb = swz_cb(blockIdx.x);
    const int tid = threadIdx.x;
    const int lane = tid & 63, wv = tid >> 6;

    int off0 = 0, len = 0;
    if (tid < NCHUNK) {
        int a0 = (int)aux[(long long)tid * AUXW + cb];
        int a1 = (int)aux[(long long)tid * AUXW + cb + 1];
        a0 = min(a0, CHUNK); a1 = min(a1, CHUNK);
        off0 = a0; len = max(a1 - a0, 0);
    }
    roff[tid] = off0;
    for (int i = tid; i < SPB; i += 512) { cnt[i] = 0; lcur[i] = 0; }

    int iv = len;
    #pragma unroll
    for (int off = 1; off < 64; off <<= 1) {
        int t = __shfl_up(iv, off, 64);
        if (lane >= off) iv += t;
    }
    if (lane == 63) wsum[wv] = iv;
    __syncthreads();
    int wbase = 0;
    #pragma unroll
    for (int k = 0; k < 8; ++k) wbase += (k < wv) ? wsum[k] : 0;
    rb[tid] = wbase + iv;
    __syncthreads();
    const int nb = min(rb[511], CAP);

    for (int i = tid; i < nb; i += 512) {
        int j = 0;
        #pragma unroll
        for (int s = 256; s > 0; s >>= 1) {
            int k = j + s;
            if (k <= 512 && rb[k - 1] <= i) j = k;
        }
        j = min(j, 511);
        int prev = (j > 0) ? rb[j - 1] : 0;
        int local = i - prev;
        long long pidx = (long long)j * CHUNK + roff[j] + local;
        pidx = min(max(pidx, 0LL), PAIRN - 1);
        int2 v = pair[pidx];
        spu[i] = v;
        atomicAdd(&cnt[(v.x >> 18) & (SPB - 1)], 1);
    }
    __syncthreads();

    int cv = (tid < SPB) ? cnt[tid] : 0;
    int iv2 = cv;
    #pragma unroll
    for (int off = 1; off < 64; off <<= 1) {
        int t = __shfl_up(iv2, off, 64);
        if (lane >= off) iv2 += t;
    }
    if (tid == 63) wsum[0] = iv2;
    __syncthreads();
    if (tid < SPB) scn[tid] = iv2 - cv + ((tid >= 64) ? wsum[0] : 0);
    __syncthreads();

    for (int i = tid; i < nb; i += 512) {
        int2 v = spu[i];
        int sl = (v.x >> 18) & (SPB - 1);
        int pos = scn[sl] + atomicAdd(&lcur[sl], 1);
        pos = min(max(pos, 0), CAP - 1);
        sps[pos] = v;
    }
    if (tid < 8) { int2 z; z.x = 0; z.y = 0; sps[min(nb + tid, CAP + 7)] = z; }
    __syncthreads();

    const int wid  = tid >> 6;
    const int half = lane >> 5;
    const int sub  = lane & 31;
    const float2* H2 = (const float2*)H;

    for (int s = 0; s < 16; ++s) {
        int sl = wid * 16 + s;
        int st = scn[sl];
        int en = st + cnt[sl];
        float ax = 0.f, ay = 0.f;
        for (int i = st; i < en; i += 8) {
            int2 p0 = sps[min(i + half,     CAP + 7)];
            int2 p1 = sps[min(i + 2 + half, CAP + 7)];
            int2 p2 = sps[min(i + 4 + half, CAP + 7)];
            int2 p3 = sps[min(i + 6 + half, CAP + 7)];
            float2 h0 = H2[((uint)min(p0.x & 0x3FFFF, NSEG - 1) << 5) + sub];
            float2 h1 = H2[((uint)min(p1.x & 0x3FFFF, NSEG - 1) << 5) + sub];
            float2 h2 = H2[((uint)min(p2.x & 0x3FFFF, NSEG - 1) << 5) + sub];
            float2 h3 = H2[((uint)min(p3.x & 0x3FFFF, NSEG - 1) << 5) + sub];
            float w0 = (i + half     < en) ? __int_as_float(p0.y) : 0.0f;
            float w1 = (i + 2 + half < en) ? __int_as_float(p1.y) : 0.0f;
            float w2 = (i + 4 + half < en) ? __int_as_float(p2.y) : 0.0f;
            float w3 = (i + 6 + half < en) ? __int_as_float(p3.y) : 0.0f;
            ax = fmaf(w0, h0.x, ax);
            ay = fmaf(w0, h0.y, ay);
            ax = fmaf(w1, h1.x, ax);
            ay = fmaf(w1, h1.y, ay);
            ax = fmaf(w2, h2.x, ax);
            ay = fmaf(w2, h2.y, ay);
            ax = fmaf(w3, h3.x, ax);
            ay = fmaf(w3, h3.y, ay);
        }
        ax += __shfl_xor(ax, 32, 64);
        ay += __shfl_xor(ay, 32, 64);
        int seg = (cb << 7) + sl;
        if (half == 0 && seg < NSEG) {
            float2 v2; v2.x = ax; v2.y = ay;
            ((float2*)out)[((long long)seg << 5) + sub] = v2;
        }
    }
}

// ---------- Fallback path (ws too small): zero + atomic scatter ----------
__global__ __launch_bounds__(256) void zero_kernel(int* __restrict__ p, long long n)
{
    long long i = (long long)blockIdx.x * blockDim.x + threadIdx.x;
    if (i < n) p[i] = 0;
}

__global__ __launch_bounds__(256) void atomic_kernel(
    const float* __restrict__ H, const float* __restrict__ ew,
    float* __restrict__ out)
{
    const long long gid = (long long)blockIdx.x * blockDim.x + threadIdx.x;
    const long long wave = gid >> 6;
    const int lane = threadIdx.x & 63;
    if (wave >= (long long)NEDGE) return;
    const int b = (int)(wave / N_EDGES);
    const long long ebase = wave * 3;
    const int src = (int)ew[ebase + 0];
    const int dst = (int)ew[ebase + 1];
    const float w = ew[ebase + 2];
    atomicAdd(&out[((long long)b * N_NODES + src) * H_SIZE + lane],
              w * H[((long long)b * N_NODES + dst) * H_SIZE + lane]);
}

extern "C" void kernel_launch(void* const* d_in, const int* in_sizes, int n_in,
                              void* d_out, int out_size, void* d_ws, size_t ws_size,
                              hipStream_t stream) {
    const float* H  = (const float*)d_in[0];   // (B, N, 64) fp32
    const float* ew = (const float*)d_in[1];   // (B, E, 3) fp32
    float* out = (float*)d_out;                // (B, N, 64) fp32

    // ws layout: aux[NCHUNK*AUXW]ushort | (16B) pair[NCHUNK*CHUNK]int2 |
    //            (128B) Hb16[12.8M ushort]
    const size_t aux_bytes = (size_t)NCHUNK * AUXW * 2;
    const size_t p_off = (aux_bytes + 15) & ~(size_t)15;
    const size_t h_off = (p_off + (size_t)PAIRN * 8 + 127) & ~(size_t)127;
    const size_t need_base = h_off;                     // ~17.6 MB (fp32 gather)
    const size_t need_full = h_off + (size_t)NHEL * 2;  // ~43.2 MB (bf16 gather)

    if (ws_size < need_base) {
        long long n = out_size;
        zero_kernel<<<(unsigned)((n + 255) / 256), 256, 0, stream>>>((int*)out, n);
        const long long total = (long long)NEDGE * 64;
        atomic_kernel<<<(unsigned)((total + 255) / 256), 256, 0, stream>>>(H, ew, out);
        return;
    }

    ushort* aux = (ushort*)d_ws;
    int2* pair  = (int2*)((char*)d_ws + p_off);
    ushort* Hb16 = (ushort*)((char*)d_ws + h_off);

    const bool full = (ws_size >= need_full);

    bin_kernel<<<NCHUNK, 512, 0, stream>>>(ew, aux, pair, H, Hb16, full ? 1 : 0);

    if (full) {
        sortgather_bf16<<<CB, 512, 0, stream>>>(Hb16, aux, pair, out);
    } else {
        sortgather_f32<<<CB, 512, 0, stream>>>(H, aux, pair, out);
    }
}

// Round 10
// 160.422 us; speedup vs baseline: 1.1331x; 1.0256x over previous
//
#include <hip/hip_runtime.h>

#define N_NODES 50000
#define BATCH   4
#define N_EDGES 500000
#define H_SIZE  64

#define NSEG   (BATCH * N_NODES)            // 200,000 segments (b, src)
#define NEDGE  (BATCH * N_EDGES)            // 2,000,000 edges
#define NHEL   ((long long)BATCH * N_NODES * H_SIZE)   // 12.8M H elems

#define SPB    128                          // segments per bucket (seg>>7)
#define CB     ((NSEG + SPB - 1) / SPB)     // 1563 buckets
#define CAP    2048                         // per-bucket LDS edge cap (mean 1280, +21 sigma)
#define CHUNK  4096                         // edges per bin block
#define NCHUNK ((NEDGE + CHUNK - 1) / CHUNK) // 489 (<512, fits one scan row)
#define AUXW   (CB + 1)                     // aux row: starts + sentinel
#define BINS   2048                         // padded bin count (>= CB+1)
#define PAIRN  ((long long)NCHUNK * CHUNK)  // allocated pair entries

// ---------- Phase 1: per-chunk bucket binning + fused H->bf16 cvt ----------
// 1024 threads (4 edges/thread, compile-time indexed): grid 489 blocks is
// only ~1.9/CU, so bigger blocks -> ~30 waves/CU to hide ew+cvt latency.
// pair.x = (sl<<18) | gdst  where sl = seg&127, gdst = b*N_NODES+dst (<2^18)
__global__ __launch_bounds__(1024) void bin_kernel(
    const float* __restrict__ ew, ushort* __restrict__ aux,
    int2* __restrict__ pair,
    const float* __restrict__ H, ushort* __restrict__ Hb16, int do_cvt)
{
    __shared__ int2 st[CHUNK];     // 32 KB sorted staging
    __shared__ int cnt[BINS];      // 8 KB
    __shared__ int scn[BINS];      // 8 KB (starts -> placement cursors)
    __shared__ int wsum[16];
    const int c = blockIdx.x;
    const int tid = threadIdx.x;
    const int lane = tid & 63, wv = tid >> 6;
    const int e0 = c * CHUNK;
    const int n = min(CHUNK, NEDGE - e0);

    for (int i = tid; i < BINS; i += 1024) cnt[i] = 0;
    __syncthreads();

    // exactly 4 edges per thread, compile-time indexed (no scratch)
    int2 ev[4];
    int  ecb[4];
    #pragma unroll
    for (int k = 0; k < 4; ++k) {
        int i = tid + 1024 * k;
        if (i < n) {
            int e = e0 + i;
            long long eb = (long long)e * 3;
            int b = e / N_EDGES;
            int src = (int)ew[eb];
            int dst = (int)ew[eb + 1];
            float w = ew[eb + 2];
            src = min(max(src, 0), N_NODES - 1);
            dst = min(max(dst, 0), N_NODES - 1);
            int seg = b * N_NODES + src;
            int cb = seg >> 7, sl = seg & (SPB - 1);
            int2 v; v.x = (sl << 18) | (b * N_NODES + dst); v.y = __float_as_int(w);
            ev[k] = v; ecb[k] = cb;
            atomicAdd(&cnt[cb], 1);
        } else {
            ecb[k] = -1;
        }
    }
    __syncthreads();

    // exclusive scan of 2048 bins: 2 bins/thread + shfl wave scan (16 waves)
    int c0 = cnt[2 * tid], c1 = cnt[2 * tid + 1];
    int tot = c0 + c1;
    int iv = tot;
    #pragma unroll
    for (int off = 1; off < 64; off <<= 1) {
        int t = __shfl_up(iv, off, 64);
        if (lane >= off) iv += t;
    }
    if (lane == 63) wsum[wv] = iv;
    __syncthreads();
    int wbase = 0;
    #pragma unroll
    for (int k = 0; k < 16; ++k) wbase += (k < wv) ? wsum[k] : 0;
    int base = wbase + iv - tot;          // exclusive prefix of this thread's 2 bins
    scn[2 * tid]     = base;
    scn[2 * tid + 1] = base + c0;
    __syncthreads();

    // write chunk-local bucket starts (before cursors get consumed)
    for (int i = tid; i < AUXW; i += 1024)
        aux[(long long)c * AUXW + i] = (ushort)scn[i];
    __syncthreads();

    // place edges into sorted LDS staging (compile-time k)
    #pragma unroll
    for (int k = 0; k < 4; ++k) {
        if (ecb[k] >= 0) {
            int pos = atomicAdd(&scn[ecb[k]], 1);
            st[min(pos, CHUNK - 1)] = ev[k];
        }
    }
    __syncthreads();

    // coalesced writeout (2 edges = int4 per op)
    for (int i = 2 * tid; i + 1 < n; i += 2048)
        *(int4*)(pair + (long long)e0 + i) = *(const int4*)(st + i);
    if (tid == 0 && (n & 1)) pair[(long long)e0 + n - 1] = st[n - 1];

    // fused cvt: H fp32 -> bf16 (RNE), grid-stride
    if (do_cvt) {
        const long long stride = (long long)NCHUNK * 1024 * 4;
        for (long long i = ((long long)c * 1024 + tid) * 4; i < NHEL; i += stride) {
            float4 f = *(const float4*)(H + i);
            ushort4 u;
            uint v;
            v = __float_as_uint(f.x); u.x = (ushort)((v + 0x7FFF + ((v >> 16) & 1)) >> 16);
            v = __float_as_uint(f.y); u.y = (ushort)((v + 0x7FFF + ((v >> 16) & 1)) >> 16);
            v = __float_as_uint(f.z); u.z = (ushort)((v + 0x7FFF + ((v >> 16) & 1)) >> 16);
            v = __float_as_uint(f.w); u.w = (ushort)((v + 0x7FFF + ((v >> 16) & 1)) >> 16);
            *(ushort4*)(Hb16 + i) = u;
        }
    }
}

// XCD-affinity bijective block->bucket map (proven R7: FETCH 125->76 MB;
// bf16 per-XCD slice ~3.2 MB fits the 4 MB L2).
__device__ __forceinline__ int swz_cb(int bid)
{
    const int q = CB >> 3, r = CB & 7;     // 195, 3
    int xcd = bid & 7, idx = bid >> 3;
    return (xcd < r) ? (xcd * (q + 1) + idx)
                     : (r * (q + 1) + (xcd - r) * q + idx);
}

// ---------- Phase 2: fused counting-sort (LDS) + register gather ----------
// Quarter-wave gather: lane = (edge slot q = lane>>4, feat quad fq = lane&15).
// Each lane loads uint2 = 4 bf16 feats -> one load inst covers 4 edges/wave
// (2x fewer loads, 2x fewer FMA insts vs R9 half-wave). A/B segment pairing
// kept (2 H-loads in flight). Cross-quarter butterfly reduce; lanes 0-15
// write A's row, 16-31 write B's (float4, coalesced). All indices clamped.
__global__ __launch_bounds__(512) void sortgather_bf16(
    const ushort* __restrict__ Hb16, const ushort* __restrict__ aux,
    const int2* __restrict__ pair, float* __restrict__ out)
{
    __shared__ int2 spu[CAP];          // 16 KB unsorted staging
    __shared__ int2 sps[CAP + 16];     // 16 KB + pad sorted
    __shared__ int rb[512];            // inclusive run-length scan
    __shared__ int roff[512];          // run start offset within chunk
    __shared__ int cnt[SPB];
    __shared__ int scn[SPB];
    __shared__ int lcur[SPB];
    __shared__ int wsum[8];
    const int cb = swz_cb(blockIdx.x);
    const int tid = threadIdx.x;
    const int lane = tid & 63, wv = tid >> 6;

    // run descriptor for chunk tid
    int off0 = 0, len = 0;
    if (tid < NCHUNK) {
        int a0 = (int)aux[(long long)tid * AUXW + cb];
        int a1 = (int)aux[(long long)tid * AUXW + cb + 1];
        a0 = min(a0, CHUNK); a1 = min(a1, CHUNK);
        off0 = a0; len = max(a1 - a0, 0);
    }
    roff[tid] = off0;
    for (int i = tid; i < SPB; i += 512) { cnt[i] = 0; lcur[i] = 0; }

    // shfl-based inclusive scan of run lengths -> rb[]
    int iv = len;
    #pragma unroll
    for (int off = 1; off < 64; off <<= 1) {
        int t = __shfl_up(iv, off, 64);
        if (lane >= off) iv += t;
    }
    if (lane == 63) wsum[wv] = iv;
    __syncthreads();
    int wbase = 0;
    #pragma unroll
    for (int k = 0; k < 8; ++k) wbase += (k < wv) ? wsum[k] : 0;
    rb[tid] = wbase + iv;
    __syncthreads();
    const int nb = min(rb[511], CAP);

    // cooperative copy: edge i -> (chunk j, local) via binary search over rb
    for (int i = tid; i < nb; i += 512) {
        int j = 0;
        #pragma unroll
        for (int s = 256; s > 0; s >>= 1) {
            int k = j + s;
            if (k <= 512 && rb[k - 1] <= i) j = k;
        }
        j = min(j, 511);
        int prev = (j > 0) ? rb[j - 1] : 0;
        int local = i - prev;
        long long pidx = (long long)j * CHUNK + roff[j] + local;
        pidx = min(max(pidx, 0LL), PAIRN - 1);
        int2 v = pair[pidx];
        spu[i] = v;
        atomicAdd(&cnt[(v.x >> 18) & (SPB - 1)], 1);
    }
    __syncthreads();

    // exclusive scan of SPB bins (shfl scan + cross-wave base)
    int cv = (tid < SPB) ? cnt[tid] : 0;
    int iv2 = cv;
    #pragma unroll
    for (int off = 1; off < 64; off <<= 1) {
        int t = __shfl_up(iv2, off, 64);
        if (lane >= off) iv2 += t;
    }
    if (tid == 63) wsum[0] = iv2;
    __syncthreads();
    if (tid < SPB) scn[tid] = iv2 - cv + ((tid >= 64) ? wsum[0] : 0);
    __syncthreads();

    // LDS -> LDS counting sort
    for (int i = tid; i < nb; i += 512) {
        int2 v = spu[i];
        int sl = (v.x >> 18) & (SPB - 1);
        int pos = scn[sl] + atomicAdd(&lcur[sl], 1);
        pos = min(max(pos, 0), CAP - 1);
        sps[pos] = v;
    }
    // zero 16-entry pad past nb (read by unguarded loads; w=0 kills them)
    if (tid < 16) { int2 z; z.x = 0; z.y = 0; sps[min(nb + tid, CAP + 15)] = z; }
    __syncthreads();

    // gather: wave w owns segments w*16 .. w*16+15, processed in pairs
    const int wid = tid >> 6;
    const int q   = lane >> 4;         // edge slot within round (0..3)
    const int fq  = lane & 15;         // feature quad
    const uint2* H2u = (const uint2*)Hb16;

    for (int s = 0; s < 16; s += 2) {
        int slA = wid * 16 + s, slB = slA + 1;
        int stA = scn[slA], enA = stA + cnt[slA];
        int stB = scn[slB], enB = stB + cnt[slB];
        int rounds = (max(enA - stA, enB - stB) + 3) >> 2;
        float a0 = 0.f, a1 = 0.f, a2 = 0.f, a3 = 0.f;
        float b0 = 0.f, b1 = 0.f, b2 = 0.f, b3 = 0.f;
        int iA = stA, iB = stB;
        for (int r = 0; r < rounds; ++r, iA += 4, iB += 4) {
            int eA = iA + q, eB = iB + q;
            int2 pA = sps[min(eA, CAP + 15)];
            int2 pB = sps[min(eB, CAP + 15)];
            uint2 hA = H2u[((uint)min(pA.x & 0x3FFFF, NSEG - 1) << 4) + fq];
            uint2 hB = H2u[((uint)min(pB.x & 0x3FFFF, NSEG - 1) << 4) + fq];
            float wA = (eA < enA) ? __int_as_float(pA.y) : 0.0f;
            float wB = (eB < enB) ? __int_as_float(pB.y) : 0.0f;
            a0 = fmaf(wA, __uint_as_float(hA.x << 16), a0);
            a1 = fmaf(wA, __uint_as_float(hA.x & 0xFFFF0000u), a1);
            a2 = fmaf(wA, __uint_as_float(hA.y << 16), a2);
            a3 = fmaf(wA, __uint_as_float(hA.y & 0xFFFF0000u), a3);
            b0 = fmaf(wB, __uint_as_float(hB.x << 16), b0);
            b1 = fmaf(wB, __uint_as_float(hB.x & 0xFFFF0000u), b1);
            b2 = fmaf(wB, __uint_as_float(hB.y << 16), b2);
            b3 = fmaf(wB, __uint_as_float(hB.y & 0xFFFF0000u), b3);
        }
        // cross-quarter butterfly: every lane ends with the full sum for its fq
        a0 += __shfl_xor(a0, 16, 64); a0 += __shfl_xor(a0, 32, 64);
        a1 += __shfl_xor(a1, 16, 64); a1 += __shfl_xor(a1, 32, 64);
        a2 += __shfl_xor(a2, 16, 64); a2 += __shfl_xor(a2, 32, 64);
        a3 += __shfl_xor(a3, 16, 64); a3 += __shfl_xor(a3, 32, 64);
        b0 += __shfl_xor(b0, 16, 64); b0 += __shfl_xor(b0, 32, 64);
        b1 += __shfl_xor(b1, 16, 64); b1 += __shfl_xor(b1, 32, 64);
        b2 += __shfl_xor(b2, 16, 64); b2 += __shfl_xor(b2, 32, 64);
        b3 += __shfl_xor(b3, 16, 64); b3 += __shfl_xor(b3, 32, 64);
        int segA = (cb << 7) + slA;
        int segB = segA + 1;
        if (q == 0 && segA < NSEG) {       // lanes 0..15 write A
            float4 v; v.x = a0; v.y = a1; v.z = a2; v.w = a3;
            ((float4*)out)[((long long)segA << 4) + fq] = v;
        }
        if (q == 1 && segB < NSEG) {       // lanes 16..31 write B
            float4 v; v.x = b0; v.y = b1; v.z = b2; v.w = b3;
            ((float4*)out)[((long long)segB << 4) + fq] = v;
        }
    }
}

// fp32 fallback gather (workspace too small for the bf16 mirror) — R9's
// proven ILP-8 variant, unchanged.
__global__ __launch_bounds__(512) void sortgather_f32(
    const float* __restrict__ H, const ushort* __restrict__ aux,
    const int2* __restrict__ pair, float* __restrict__ out)
{
    __shared__ int2 spu[CAP];
    __shared__ int2 sps[CAP + 8];
    __shared__ int rb[512];
    __shared__ int roff[512];
    __shared__ int cnt[SPB];
    __shared__ int scn[SPB];
    __shared__ int lcur[SPB];
    __shared__ int wsum[8];
    const int cb = swz_cb(blockIdx.x);
    const int tid = threadIdx.x;
    const int lane = tid & 63, wv = tid >> 6;

    int off0 = 0, len = 0;
    if (tid < NCHUNK) {
        int a0 = (int)aux[(long long)tid * AUXW + cb];
        int a1 = (int)aux[(long long)tid * AUXW + cb + 1];
        a0 = min(a0, CHUNK); a1 = min(a1, CHUNK);
        off0 = a0; len = max(a1 - a0, 0);
    }
    roff[tid] = off0;
    for (int i = tid; i < SPB; i += 512) { cnt[i] = 0; lcur[i] = 0; }

    int iv = len;
    #pragma unroll
    for (int off = 1; off < 64; off <<= 1) {
        int t = __shfl_up(iv, off, 64);
        if (lane >= off) iv += t;
    }
    if (lane == 63) wsum[wv] = iv;
    __syncthreads();
    int wbase = 0;
    #pragma unroll
    for (int k = 0; k < 8; ++k) wbase += (k < wv) ? wsum[k] : 0;
    rb[tid] = wbase + iv;
    __syncthreads();
    const int nb = min(rb[511], CAP);

    for (int i = tid; i < nb; i += 512) {
        int j = 0;
        #pragma unroll
        for (int s = 256; s > 0; s >>= 1) {
            int k = j + s;
            if (k <= 512 && rb[k - 1] <= i) j = k;
        }
        j = min(j, 511);
        int prev = (j > 0) ? rb[j - 1] : 0;
        int local = i - prev;
        long long pidx = (long long)j * CHUNK + roff[j] + local;
        pidx = min(max(pidx, 0LL), PAIRN - 1);
        int2 v = pair[pidx];
        spu[i] = v;
        atomicAdd(&cnt[(v.x >> 18) & (SPB - 1)], 1);
    }
    __syncthreads();

    int cv = (tid < SPB) ? cnt[tid] : 0;
    int iv2 = cv;
    #pragma unroll
    for (int off = 1; off < 64; off <<= 1) {
        int t = __shfl_up(iv2, off, 64);
        if (lane >= off) iv2 += t;
    }
    if (tid == 63) wsum[0] = iv2;
    __syncthreads();
    if (tid < SPB) scn[tid] = iv2 - cv + ((tid >= 64) ? wsum[0] : 0);
    __syncthreads();

    for (int i = tid; i < nb; i += 512) {
        int2 v = spu[i];
        int sl = (v.x >> 18) & (SPB - 1);
        int pos = scn[sl] + atomicAdd(&lcur[sl], 1);
        pos = min(max(pos, 0), CAP - 1);
        sps[pos] = v;
    }
    if (tid < 8) { int2 z; z.x = 0; z.y = 0; sps[min(nb + tid, CAP + 7)] = z; }
    __syncthreads();

    const int wid  = tid >> 6;
    const int half = lane >> 5;
    const int sub  = lane & 31;
    const float2* H2 = (const float2*)H;

    for (int s = 0; s < 16; ++s) {
        int sl = wid * 16 + s;
        int st = scn[sl];
        int en = st + cnt[sl];
        float ax = 0.f, ay = 0.f;
        for (int i = st; i < en; i += 8) {
            int2 p0 = sps[min(i + half,     CAP + 7)];
            int2 p1 = sps[min(i + 2 + half, CAP + 7)];
            int2 p2 = sps[min(i + 4 + half, CAP + 7)];
            int2 p3 = sps[min(i + 6 + half, CAP + 7)];
            float2 h0 = H2[((uint)min(p0.x & 0x3FFFF, NSEG - 1) << 5) + sub];
            float2 h1 = H2[((uint)min(p1.x & 0x3FFFF, NSEG - 1) << 5) + sub];
            float2 h2 = H2[((uint)min(p2.x & 0x3FFFF, NSEG - 1) << 5) + sub];
            float2 h3 = H2[((uint)min(p3.x & 0x3FFFF, NSEG - 1) << 5) + sub];
            float w0 = (i + half     < en) ? __int_as_float(p0.y) : 0.0f;
            float w1 = (i + 2 + half < en) ? __int_as_float(p1.y) : 0.0f;
            float w2 = (i + 4 + half < en) ? __int_as_float(p2.y) : 0.0f;
            float w3 = (i + 6 + half < en) ? __int_as_float(p3.y) : 0.0f;
            ax = fmaf(w0, h0.x, ax);
            ay = fmaf(w0, h0.y, ay);
            ax = fmaf(w1, h1.x, ax);
            ay = fmaf(w1, h1.y, ay);
            ax = fmaf(w2, h2.x, ax);
            ay = fmaf(w2, h2.y, ay);
            ax = fmaf(w3, h3.x, ax);
            ay = fmaf(w3, h3.y, ay);
        }
        ax += __shfl_xor(ax, 32, 64);
        ay += __shfl_xor(ay, 32, 64);
        int seg = (cb << 7) + sl;
        if (half == 0 && seg < NSEG) {
            float2 v2; v2.x = ax; v2.y = ay;
            ((float2*)out)[((long long)seg << 5) + sub] = v2;
        }
    }
}

// ---------- Fallback path (ws too small): zero + atomic scatter ----------
__global__ __launch_bounds__(256) void zero_kernel(int* __restrict__ p, long long n)
{
    long long i = (long long)blockIdx.x * blockDim.x + threadIdx.x;
    if (i < n) p[i] = 0;
}

__global__ __launch_bounds__(256) void atomic_kernel(
    const float* __restrict__ H, const float* __restrict__ ew,
    float* __restrict__ out)
{
    const long long gid = (long long)blockIdx.x * blockDim.x + threadIdx.x;
    const long long wave = gid >> 6;
    const int lane = threadIdx.x & 63;
    if (wave >= (long long)NEDGE) return;
    const int b = (int)(wave / N_EDGES);
    const long long ebase = wave * 3;
    const int src = (int)ew[ebase + 0];
    const int dst = (int)ew[ebase + 1];
    const float w = ew[ebase + 2];
    atomicAdd(&out[((long long)b * N_NODES + src) * H_SIZE + lane],
              w * H[((long long)b * N_NODES + dst) * H_SIZE + lane]);
}

extern "C" void kernel_launch(void* const* d_in, const int* in_sizes, int n_in,
                              void* d_out, int out_size, void* d_ws, size_t ws_size,
                              hipStream_t stream) {
    const float* H  = (const float*)d_in[0];   // (B, N, 64) fp32
    const float* ew = (const float*)d_in[1];   // (B, E, 3) fp32
    float* out = (float*)d_out;                // (B, N, 64) fp32

    // ws layout: aux[NCHUNK*AUXW]ushort | (16B) pair[NCHUNK*CHUNK]int2 |
    //            (128B) Hb16[12.8M ushort]
    const size_t aux_bytes = (size_t)NCHUNK * AUXW * 2;
    const size_t p_off = (aux_bytes + 15) & ~(size_t)15;
    const size_t h_off = (p_off + (size_t)PAIRN * 8 + 127) & ~(size_t)127;
    const size_t need_base = h_off;                     // ~17.6 MB (fp32 gather)
    const size_t need_full = h_off + (size_t)NHEL * 2;  // ~43.2 MB (bf16 gather)

    if (ws_size < need_base) {
        long long n = out_size;
        zero_kernel<<<(unsigned)((n + 255) / 256), 256, 0, stream>>>((int*)out, n);
        const long long total = (long long)NEDGE * 64;
        atomic_kernel<<<(unsigned)((total + 255) / 256), 256, 0, stream>>>(H, ew, out);
        return;
    }

    ushort* aux = (ushort*)d_ws;
    int2* pair  = (int2*)((char*)d_ws + p_off);
    ushort* Hb16 = (ushort*)((char*)d_ws + h_off);

    const bool full = (ws_size >= need_full);

    bin_kernel<<<NCHUNK, 1024, 0, stream>>>(ew, aux, pair, H, Hb16, full ? 1 : 0);

    if (full) {
        sortgather_bf16<<<CB, 512, 0, stream>>>(Hb16, aux, pair, out);
    } else {
        sortgather_f32<<<CB, 512, 0, stream>>>(H, aux, pair, out);
    }
}